// Round 1
// baseline (618.459 us; speedup 1.0000x reference)
//
#include <hip/hip_runtime.h>

#define NN 50000
#define NE 800000
#define NG 500
#define IND 128
#define HD 96
#define OD 64

// ---------------- CSR build ----------------

__global__ void zero_k(int* __restrict__ cnt, int* __restrict__ fill,
                       int* __restrict__ gcnt, float* __restrict__ P) {
  int i = blockIdx.x * 256 + threadIdx.x;
  if (i < NN) { cnt[i] = 0; fill[i] = 0; }
  if (i < NG) gcnt[i] = 0;
  if (i < 3 * NG * HD) P[i] = 0.f;
}

__global__ void hist_k(const int* __restrict__ dst, int* __restrict__ cnt) {
  int i = blockIdx.x * 256 + threadIdx.x;
  if (i < NE) atomicAdd(&cnt[dst[i]], 1);
}

__global__ void gcnt_k(const int* __restrict__ batch, int* __restrict__ gcnt) {
  int i = blockIdx.x * 256 + threadIdx.x;
  if (i < NN) atomicAdd(&gcnt[batch[i]], 1);
}

// single-block exclusive scan over 50000 counts; also emits dinv = rsqrt(deg+1)
__global__ __launch_bounds__(1024) void scan_k(const int* __restrict__ cnt,
                                               int* __restrict__ row_ptr,
                                               float* __restrict__ dinv) {
  __shared__ int s[1024];
  int tid = threadIdx.x;
  const int per = (NN + 1023) / 1024;  // 49
  int start = tid * per;
  int end = start + per; if (end > NN) end = NN;
  int sum = 0;
  for (int i = start; i < end; i++) sum += cnt[i];
  s[tid] = sum;
  __syncthreads();
  for (int off = 1; off < 1024; off <<= 1) {
    int v = (tid >= off) ? s[tid - off] : 0;
    __syncthreads();
    s[tid] += v;
    __syncthreads();
  }
  int run = (tid == 0) ? 0 : s[tid - 1];
  for (int i = start; i < end; i++) {
    row_ptr[i] = run;
    run += cnt[i];
    dinv[i] = rsqrtf((float)(cnt[i] + 1));  // +1 self loop, always >= 1
  }
  if (tid == 1023) row_ptr[NN] = s[1023];
}

__global__ void fill_k(const int* __restrict__ src, const int* __restrict__ dst,
                       const int* __restrict__ row_ptr, int* __restrict__ fill,
                       int* __restrict__ col) {
  int i = blockIdx.x * 256 + threadIdx.x;
  if (i < NE) {
    int d = dst[i];
    int slot = row_ptr[d] + atomicAdd(&fill[d], 1);
    col[slot] = src[i];
  }
}

// ---------------- g = (h @ W) * dinv[:,None]  (fp32, LDS-tiled) ----------------
// block = 256 threads, 64 rows/block; thread = (row r=tid>>2, 24-col group cg)
template <int K>
__global__ __launch_bounds__(256) void gemm_scale_k(const float* __restrict__ h,
                                                    const float* __restrict__ W,
                                                    const float* __restrict__ dinv,
                                                    float* __restrict__ g) {
  __shared__ float hs[64][65];                                   // +1 pad: conflict-free
  __shared__ __attribute__((aligned(16))) float ws[64][100];     // stride 100 (%4==0 for f4)
  const int tid = threadIdx.x;
  const int r = tid >> 2;
  const int cg = (tid & 3) * 24;
  const int row0 = blockIdx.x * 64;
  const int row = row0 + r;
  float acc[24];
#pragma unroll
  for (int j = 0; j < 24; j++) acc[j] = 0.f;

  for (int k0 = 0; k0 < K; k0 += 64) {
    const int kc = (K - k0 >= 64) ? 64 : (K - k0);  // 64 or 32 (both pow2)
    const int ksh = (kc == 64) ? 6 : 5;
    // stage h tile (coalesced)
    for (int lin = tid; lin < (64 << ksh); lin += 256) {
      int rr = lin >> ksh, kk = lin & (kc - 1);
      int grow = row0 + rr;
      hs[rr][kk] = (grow < NN) ? h[(long)grow * K + k0 + kk] : 0.f;
    }
    // stage W chunk (coalesced)
    for (int lin = tid; lin < kc * HD; lin += 256) {
      int kk = lin / HD, cc = lin - kk * HD;
      ws[kk][cc] = W[(long)(k0 + kk) * HD + cc];
    }
    __syncthreads();
#pragma unroll 8
    for (int k = 0; k < kc; k++) {
      float a = hs[r][k];
#pragma unroll
      for (int j = 0; j < 6; j++) {
        float4 w = *reinterpret_cast<const float4*>(&ws[k][cg + 4 * j]);
        acc[4 * j + 0] = fmaf(a, w.x, acc[4 * j + 0]);
        acc[4 * j + 1] = fmaf(a, w.y, acc[4 * j + 1]);
        acc[4 * j + 2] = fmaf(a, w.z, acc[4 * j + 2]);
        acc[4 * j + 3] = fmaf(a, w.w, acc[4 * j + 3]);
      }
    }
    __syncthreads();
  }
  if (row < NN) {
    float dv = dinv[row];
    float* go = g + (long)row * HD + cg;
#pragma unroll
    for (int j = 0; j < 6; j++) {
      float4 o;
      o.x = acc[4 * j + 0] * dv;
      o.y = acc[4 * j + 1] * dv;
      o.z = acc[4 * j + 2] * dv;
      o.w = acc[4 * j + 3] * dv;
      *reinterpret_cast<float4*>(go + 4 * j) = o;
    }
  }
}

// ---------------- CSR gather + relu + fused graph pooling ----------------
// one wave per node; lane l owns col l (and col 64+l for l<32)
template <bool WRITE_H>
__global__ __launch_bounds__(256) void gather_k(const float* __restrict__ g,
                                                const int* __restrict__ row_ptr,
                                                const int* __restrict__ col,
                                                const float* __restrict__ dinv,
                                                const float* __restrict__ bias,
                                                const int* __restrict__ batch,
                                                float* __restrict__ hout,
                                                float* __restrict__ P) {
  int d = blockIdx.x * 4 + (threadIdx.x >> 6);
  int lane = threadIdx.x & 63;
  if (d >= NN) return;
  const float* gd = g + (long)d * HD;
  float acc0 = gd[lane];                 // self-loop contribution
  float acc1 = gd[64 + (lane & 31)];     // lanes>=32 duplicate (broadcast), unused later
  int e = row_ptr[d];
  const int end = row_ptr[d + 1];
  while (e < end) {
    int cnt = end - e; if (cnt > 64) cnt = 64;
    int cid = (lane < cnt) ? col[e + lane] : 0;
    for (int j = 0; j < cnt; j++) {
      int srow = __shfl(cid, j);
      const float* gs = g + (long)srow * HD;
      acc0 += gs[lane];
      acc1 += gs[64 + (lane & 31)];
    }
    e += 64;
  }
  float dv = dinv[d];
  int gr = batch[d];
  float v0 = fmaxf(fmaf(acc0, dv, bias[lane]), 0.f);
  if (WRITE_H) hout[(long)d * HD + lane] = v0;
  atomicAdd(&P[gr * HD + lane], v0);
  if (lane < 32) {
    float v1 = fmaxf(fmaf(acc1, dv, bias[64 + lane]), 0.f);
    if (WRITE_H) hout[(long)d * HD + 64 + lane] = v1;
    atomicAdd(&P[gr * HD + 64 + lane], v1);
  }
}

// ---------------- tiny dense tail: JK-proj on pooled sums + MLP ----------------

__global__ void emb_k(const float* __restrict__ P, const int* __restrict__ gcnt,
                      const float* __restrict__ Wjk, const float* __restrict__ bjk,
                      float* __restrict__ emb) {
  int idx = blockIdx.x * 256 + threadIdx.x;
  if (idx >= NG * HD) return;
  int gr = idx / HD, c = idx - gr * HD;
  const float* p1 = P + (long)gr * HD;
  const float* p2 = p1 + (long)NG * HD;
  const float* p3 = p2 + (long)NG * HD;
  float acc = (float)gcnt[gr] * bjk[c];
  for (int k = 0; k < HD; k++) {
    acc = fmaf(p1[k], Wjk[k * HD + c], acc);
    acc = fmaf(p2[k], Wjk[(HD + k) * HD + c], acc);
    acc = fmaf(p3[k], Wjk[(2 * HD + k) * HD + c], acc);
  }
  emb[idx] = acc;
}

__global__ void mlp1_k(const float* __restrict__ emb, const float* __restrict__ W,
                       const float* __restrict__ b, float* __restrict__ hid) {
  int idx = blockIdx.x * 256 + threadIdx.x;
  if (idx >= NG * HD) return;
  int gr = idx / HD, c = idx - gr * HD;
  const float* e = emb + (long)gr * HD;
  float acc = b[c];
  for (int k = 0; k < HD; k++) acc = fmaf(e[k], W[k * HD + c], acc);
  hid[idx] = fmaxf(acc, 0.f);
}

__global__ void mlp2_k(const float* __restrict__ hid, const float* __restrict__ W,
                       const float* __restrict__ b, float* __restrict__ out) {
  int idx = blockIdx.x * 256 + threadIdx.x;
  if (idx >= NG * OD) return;
  int gr = idx / OD, c = idx - gr * OD;
  const float* h = hid + (long)gr * HD;
  float acc = b[c];
  for (int k = 0; k < HD; k++) acc = fmaf(h[k], W[k * OD + c], acc);
  out[idx] = acc;
}

// ---------------- launch ----------------

extern "C" void kernel_launch(void* const* d_in, const int* in_sizes, int n_in,
                              void* d_out, int out_size, void* d_ws, size_t ws_size,
                              hipStream_t stream) {
  const float* x = (const float*)d_in[0];
  const int* ei = (const int*)d_in[1];
  const int* batch = (const int*)d_in[2];
  const float* W0 = (const float*)d_in[3];  const float* b0 = (const float*)d_in[4];
  const float* W1 = (const float*)d_in[5];  const float* b1 = (const float*)d_in[6];
  const float* W2 = (const float*)d_in[7];  const float* b2 = (const float*)d_in[8];
  const float* Wjk = (const float*)d_in[9]; const float* bjk = (const float*)d_in[10];
  const float* Wm1 = (const float*)d_in[11]; const float* bm1 = (const float*)d_in[12];
  const float* Wm2 = (const float*)d_in[13]; const float* bm2 = (const float*)d_in[14];
  const int* srcp = ei;
  const int* dstp = ei + NE;

  char* wp = (char*)d_ws;
  size_t off = 0;
  auto alloc = [&](size_t bytes) -> void* {
    void* p = wp + off;
    off += bytes;
    off = (off + 255) & ~(size_t)255;
    return p;
  };
  int* cnt   = (int*)alloc((size_t)NN * 4);
  int* rowp  = (int*)alloc((size_t)(NN + 1) * 4);
  int* fill  = (int*)alloc((size_t)NN * 4);
  int* colb  = (int*)alloc((size_t)NE * 4);
  float* dinv = (float*)alloc((size_t)NN * 4);
  int* gcnt  = (int*)alloc((size_t)NG * 4);
  float* g   = (float*)alloc((size_t)NN * HD * 4);
  float* hA  = (float*)alloc((size_t)NN * HD * 4);
  float* hB  = (float*)alloc((size_t)NN * HD * 4);
  float* P   = (float*)alloc((size_t)3 * NG * HD * 4);
  float* emb = (float*)alloc((size_t)NG * HD * 4);
  float* hid = (float*)alloc((size_t)NG * HD * 4);

  // zero accumulators (must happen every call — harness does not re-poison)
  zero_k<<<(3 * NG * HD + 255) / 256, 256, 0, stream>>>(cnt, fill, gcnt, P);

  // CSR build + degrees
  hist_k<<<(NE + 255) / 256, 256, 0, stream>>>(dstp, cnt);
  gcnt_k<<<(NN + 255) / 256, 256, 0, stream>>>(batch, gcnt);
  scan_k<<<1, 1024, 0, stream>>>(cnt, rowp, dinv);
  fill_k<<<(NE + 255) / 256, 256, 0, stream>>>(srcp, dstp, rowp, fill, colb);

  // layer 1: x[50000,128] -> hA
  gemm_scale_k<IND><<<(NN + 63) / 64, 256, 0, stream>>>(x, W0, dinv, g);
  gather_k<true><<<(NN + 3) / 4, 256, 0, stream>>>(g, rowp, colb, dinv, b0, batch, hA, P);
  // layer 2: hA -> hB
  gemm_scale_k<HD><<<(NN + 63) / 64, 256, 0, stream>>>(hA, W1, dinv, g);
  gather_k<true><<<(NN + 3) / 4, 256, 0, stream>>>(g, rowp, colb, dinv, b1, batch, hB, P + NG * HD);
  // layer 3: hB -> (pool only)
  gemm_scale_k<HD><<<(NN + 63) / 64, 256, 0, stream>>>(hB, W2, dinv, g);
  gather_k<false><<<(NN + 3) / 4, 256, 0, stream>>>(g, rowp, colb, dinv, b2, batch, hA, P + 2 * NG * HD);

  // JK cat + lin on pooled sums (linearity of pooling), then MLP head
  emb_k<<<(NG * HD + 255) / 256, 256, 0, stream>>>(P, gcnt, Wjk, bjk, emb);
  mlp1_k<<<(NG * HD + 255) / 256, 256, 0, stream>>>(emb, Wm1, bm1, hid);
  mlp2_k<<<(NG * OD + 255) / 256, 256, 0, stream>>>(hid, Wm2, bm2, (float*)d_out);
}

// Round 2
// 524.153 us; speedup vs baseline: 1.1799x; 1.1799x over previous
//
#include <hip/hip_runtime.h>

#define NN 50000
#define NE 800000
#define NG 500
#define IND 128
#define HD 96
#define OD 64

#define SCAN_CHUNK 2048
#define SCAN_BLOCKS ((NN + SCAN_CHUNK - 1) / SCAN_CHUNK)  // 25

// ---------------- CSR build ----------------

__global__ void zero_k(int* __restrict__ cnt, int* __restrict__ fill,
                       int* __restrict__ gcnt, float* __restrict__ P) {
  int i = blockIdx.x * 256 + threadIdx.x;
  if (i < NN) { cnt[i] = 0; fill[i] = 0; }
  if (i < NG) gcnt[i] = 0;
  if (i < 3 * NG * HD) P[i] = 0.f;
}

__global__ void hist_k(const int* __restrict__ dst, int* __restrict__ cnt) {
  int i = blockIdx.x * 256 + threadIdx.x;
  if (i < NE) atomicAdd(&cnt[dst[i]], 1);
}

__global__ void gcnt_k(const int* __restrict__ batch, int* __restrict__ gcnt) {
  int i = blockIdx.x * 256 + threadIdx.x;
  if (i < NN) atomicAdd(&gcnt[batch[i]], 1);
}

// phase 1: per-block partial sums over 2048-elem chunks; also dinv = rsqrt(deg+1)
__global__ __launch_bounds__(256) void scan_part_k(const int* __restrict__ cnt,
                                                   int* __restrict__ bsum,
                                                   float* __restrict__ dinv) {
  __shared__ int ts[256];
  const int tid = threadIdx.x;
  const int base = blockIdx.x * SCAN_CHUNK + tid * 8;
  int s = 0;
#pragma unroll
  for (int j = 0; j < 8; j++) {
    int idx = base + j;
    if (idx < NN) {
      int c = cnt[idx];
      s += c;
      dinv[idx] = rsqrtf((float)(c + 1));
    }
  }
  ts[tid] = s;
  __syncthreads();
  for (int off = 128; off > 0; off >>= 1) {
    if (tid < off) ts[tid] += ts[tid + off];
    __syncthreads();
  }
  if (tid == 0) bsum[blockIdx.x] = ts[0];
}

// phase 2: one wave scans the 25 block sums -> exclusive boff; row_ptr[NN]=NE
__global__ __launch_bounds__(64) void scan_top_k(const int* __restrict__ bsum,
                                                 int* __restrict__ boff,
                                                 int* __restrict__ row_ptr) {
  int tid = threadIdx.x;
  int v = (tid < SCAN_BLOCKS) ? bsum[tid] : 0;
  // inclusive scan across the wave
  for (int off = 1; off < 64; off <<= 1) {
    int u = __shfl_up(v, off);
    if (tid >= off) v += u;
  }
  if (tid < SCAN_BLOCKS) boff[tid] = v - bsum[tid];  // exclusive
  if (tid == 0) row_ptr[NN] = NE;
}

// phase 3: per-block local exclusive scan + block offset -> row_ptr
__global__ __launch_bounds__(256) void scan_fin_k(const int* __restrict__ cnt,
                                                  const int* __restrict__ boff,
                                                  int* __restrict__ row_ptr) {
  __shared__ int ts[256];
  const int tid = threadIdx.x;
  const int base = blockIdx.x * SCAN_CHUNK + tid * 8;
  int v[8];
  int s = 0;
#pragma unroll
  for (int j = 0; j < 8; j++) {
    int idx = base + j;
    v[j] = (idx < NN) ? cnt[idx] : 0;
    s += v[j];
  }
  ts[tid] = s;
  __syncthreads();
  // Hillis-Steele inclusive scan over thread sums
  for (int off = 1; off < 256; off <<= 1) {
    int t = (tid >= off) ? ts[tid - off] : 0;
    __syncthreads();
    ts[tid] += t;
    __syncthreads();
  }
  int run = ((tid == 0) ? 0 : ts[tid - 1]) + boff[blockIdx.x];
#pragma unroll
  for (int j = 0; j < 8; j++) {
    int idx = base + j;
    if (idx < NN) row_ptr[idx] = run;
    run += v[j];
  }
}

__global__ void fill_k(const int* __restrict__ src, const int* __restrict__ dst,
                       const int* __restrict__ row_ptr, int* __restrict__ fill,
                       int* __restrict__ col) {
  int i = blockIdx.x * 256 + threadIdx.x;
  if (i < NE) {
    int d = dst[i];
    int slot = row_ptr[d] + atomicAdd(&fill[d], 1);
    col[slot] = src[i];
  }
}

// ---------------- g = (h @ W) * dinv[:,None]  (fp32, LDS-tiled) ----------------
// block = 256 threads, 64 rows/block; thread = (row r=tid>>2, 24-col group cg)
template <int K>
__global__ __launch_bounds__(256) void gemm_scale_k(const float* __restrict__ h,
                                                    const float* __restrict__ W,
                                                    const float* __restrict__ dinv,
                                                    float* __restrict__ g) {
  __shared__ float hs[64][65];                                   // +1 pad: conflict-free
  __shared__ __attribute__((aligned(16))) float ws[64][100];     // stride 100 (%4==0 for f4)
  const int tid = threadIdx.x;
  const int r = tid >> 2;
  const int cg = (tid & 3) * 24;
  const int row0 = blockIdx.x * 64;
  const int row = row0 + r;
  float acc[24];
#pragma unroll
  for (int j = 0; j < 24; j++) acc[j] = 0.f;

  for (int k0 = 0; k0 < K; k0 += 64) {
    const int kc = (K - k0 >= 64) ? 64 : (K - k0);  // 64 or 32 (both pow2)
    const int ksh = (kc == 64) ? 6 : 5;
    // stage h tile (coalesced)
    for (int lin = tid; lin < (64 << ksh); lin += 256) {
      int rr = lin >> ksh, kk = lin & (kc - 1);
      int grow = row0 + rr;
      hs[rr][kk] = (grow < NN) ? h[(long)grow * K + k0 + kk] : 0.f;
    }
    // stage W chunk (coalesced)
    for (int lin = tid; lin < kc * HD; lin += 256) {
      int kk = lin / HD, cc = lin - kk * HD;
      ws[kk][cc] = W[(long)(k0 + kk) * HD + cc];
    }
    __syncthreads();
#pragma unroll 8
    for (int k = 0; k < kc; k++) {
      float a = hs[r][k];
#pragma unroll
      for (int j = 0; j < 6; j++) {
        float4 w = *reinterpret_cast<const float4*>(&ws[k][cg + 4 * j]);
        acc[4 * j + 0] = fmaf(a, w.x, acc[4 * j + 0]);
        acc[4 * j + 1] = fmaf(a, w.y, acc[4 * j + 1]);
        acc[4 * j + 2] = fmaf(a, w.z, acc[4 * j + 2]);
        acc[4 * j + 3] = fmaf(a, w.w, acc[4 * j + 3]);
      }
    }
    __syncthreads();
  }
  if (row < NN) {
    float dv = dinv[row];
    float* go = g + (long)row * HD + cg;
#pragma unroll
    for (int j = 0; j < 6; j++) {
      float4 o;
      o.x = acc[4 * j + 0] * dv;
      o.y = acc[4 * j + 1] * dv;
      o.z = acc[4 * j + 2] * dv;
      o.w = acc[4 * j + 3] * dv;
      *reinterpret_cast<float4*>(go + 4 * j) = o;
    }
  }
}

// ---------------- CSR gather + relu + fused graph pooling ----------------
// one wave per node; lane l owns col l (and col 64+l for l<32)
template <bool WRITE_H>
__global__ __launch_bounds__(256) void gather_k(const float* __restrict__ g,
                                                const int* __restrict__ row_ptr,
                                                const int* __restrict__ col,
                                                const float* __restrict__ dinv,
                                                const float* __restrict__ bias,
                                                const int* __restrict__ batch,
                                                float* __restrict__ hout,
                                                float* __restrict__ P) {
  int d = blockIdx.x * 4 + (threadIdx.x >> 6);
  int lane = threadIdx.x & 63;
  if (d >= NN) return;
  const float* gd = g + (long)d * HD;
  float acc0 = gd[lane];                 // self-loop contribution
  float acc1 = gd[64 + (lane & 31)];     // lanes>=32 duplicate (broadcast), unused later
  int e = row_ptr[d];
  const int end = row_ptr[d + 1];
  while (e < end) {
    int cnt = end - e; if (cnt > 64) cnt = 64;
    int cid = (lane < cnt) ? col[e + lane] : 0;
    for (int j = 0; j < cnt; j++) {
      int srow = __shfl(cid, j);
      const float* gs = g + (long)srow * HD;
      acc0 += gs[lane];
      acc1 += gs[64 + (lane & 31)];
    }
    e += 64;
  }
  float dv = dinv[d];
  int gr = batch[d];
  float v0 = fmaxf(fmaf(acc0, dv, bias[lane]), 0.f);
  if (WRITE_H) hout[(long)d * HD + lane] = v0;
  atomicAdd(&P[gr * HD + lane], v0);
  if (lane < 32) {
    float v1 = fmaxf(fmaf(acc1, dv, bias[64 + lane]), 0.f);
    if (WRITE_H) hout[(long)d * HD + 64 + lane] = v1;
    atomicAdd(&P[gr * HD + 64 + lane], v1);
  }
}

// ---------------- tiny dense tail: JK-proj on pooled sums + MLP ----------------

__global__ void emb_k(const float* __restrict__ P, const int* __restrict__ gcnt,
                      const float* __restrict__ Wjk, const float* __restrict__ bjk,
                      float* __restrict__ emb) {
  int idx = blockIdx.x * 256 + threadIdx.x;
  if (idx >= NG * HD) return;
  int gr = idx / HD, c = idx - gr * HD;
  const float* p1 = P + (long)gr * HD;
  const float* p2 = p1 + (long)NG * HD;
  const float* p3 = p2 + (long)NG * HD;
  float acc = (float)gcnt[gr] * bjk[c];
  for (int k = 0; k < HD; k++) {
    acc = fmaf(p1[k], Wjk[k * HD + c], acc);
    acc = fmaf(p2[k], Wjk[(HD + k) * HD + c], acc);
    acc = fmaf(p3[k], Wjk[(2 * HD + k) * HD + c], acc);
  }
  emb[idx] = acc;
}

__global__ void mlp1_k(const float* __restrict__ emb, const float* __restrict__ W,
                       const float* __restrict__ b, float* __restrict__ hid) {
  int idx = blockIdx.x * 256 + threadIdx.x;
  if (idx >= NG * HD) return;
  int gr = idx / HD, c = idx - gr * HD;
  const float* e = emb + (long)gr * HD;
  float acc = b[c];
  for (int k = 0; k < HD; k++) acc = fmaf(e[k], W[k * HD + c], acc);
  hid[idx] = fmaxf(acc, 0.f);
}

__global__ void mlp2_k(const float* __restrict__ hid, const float* __restrict__ W,
                       const float* __restrict__ b, float* __restrict__ out) {
  int idx = blockIdx.x * 256 + threadIdx.x;
  if (idx >= NG * OD) return;
  int gr = idx / OD, c = idx - gr * OD;
  const float* h = hid + (long)gr * HD;
  float acc = b[c];
  for (int k = 0; k < HD; k++) acc = fmaf(h[k], W[k * OD + c], acc);
  out[idx] = acc;
}

// ---------------- launch ----------------

extern "C" void kernel_launch(void* const* d_in, const int* in_sizes, int n_in,
                              void* d_out, int out_size, void* d_ws, size_t ws_size,
                              hipStream_t stream) {
  const float* x = (const float*)d_in[0];
  const int* ei = (const int*)d_in[1];
  const int* batch = (const int*)d_in[2];
  const float* W0 = (const float*)d_in[3];  const float* b0 = (const float*)d_in[4];
  const float* W1 = (const float*)d_in[5];  const float* b1 = (const float*)d_in[6];
  const float* W2 = (const float*)d_in[7];  const float* b2 = (const float*)d_in[8];
  const float* Wjk = (const float*)d_in[9]; const float* bjk = (const float*)d_in[10];
  const float* Wm1 = (const float*)d_in[11]; const float* bm1 = (const float*)d_in[12];
  const float* Wm2 = (const float*)d_in[13]; const float* bm2 = (const float*)d_in[14];
  const int* srcp = ei;
  const int* dstp = ei + NE;

  char* wp = (char*)d_ws;
  size_t off = 0;
  auto alloc = [&](size_t bytes) -> void* {
    void* p = wp + off;
    off += bytes;
    off = (off + 255) & ~(size_t)255;
    return p;
  };
  int* cnt   = (int*)alloc((size_t)NN * 4);
  int* rowp  = (int*)alloc((size_t)(NN + 1) * 4);
  int* fill  = (int*)alloc((size_t)NN * 4);
  int* colb  = (int*)alloc((size_t)NE * 4);
  float* dinv = (float*)alloc((size_t)NN * 4);
  int* gcnt  = (int*)alloc((size_t)NG * 4);
  int* bsum  = (int*)alloc((size_t)SCAN_BLOCKS * 4);
  int* boff  = (int*)alloc((size_t)SCAN_BLOCKS * 4);
  float* g   = (float*)alloc((size_t)NN * HD * 4);
  float* hA  = (float*)alloc((size_t)NN * HD * 4);
  float* hB  = (float*)alloc((size_t)NN * HD * 4);
  float* P   = (float*)alloc((size_t)3 * NG * HD * 4);
  float* emb = (float*)alloc((size_t)NG * HD * 4);
  float* hid = (float*)alloc((size_t)NG * HD * 4);

  // zero accumulators (must happen every call — harness does not re-poison)
  zero_k<<<(3 * NG * HD + 255) / 256, 256, 0, stream>>>(cnt, fill, gcnt, P);

  // CSR build + degrees (multi-block scan)
  hist_k<<<(NE + 255) / 256, 256, 0, stream>>>(dstp, cnt);
  gcnt_k<<<(NN + 255) / 256, 256, 0, stream>>>(batch, gcnt);
  scan_part_k<<<SCAN_BLOCKS, 256, 0, stream>>>(cnt, bsum, dinv);
  scan_top_k<<<1, 64, 0, stream>>>(bsum, boff, rowp);
  scan_fin_k<<<SCAN_BLOCKS, 256, 0, stream>>>(cnt, boff, rowp);
  fill_k<<<(NE + 255) / 256, 256, 0, stream>>>(srcp, dstp, rowp, fill, colb);

  // layer 1: x[50000,128] -> hA
  gemm_scale_k<IND><<<(NN + 63) / 64, 256, 0, stream>>>(x, W0, dinv, g);
  gather_k<true><<<(NN + 3) / 4, 256, 0, stream>>>(g, rowp, colb, dinv, b0, batch, hA, P);
  // layer 2: hA -> hB
  gemm_scale_k<HD><<<(NN + 63) / 64, 256, 0, stream>>>(hA, W1, dinv, g);
  gather_k<true><<<(NN + 3) / 4, 256, 0, stream>>>(g, rowp, colb, dinv, b1, batch, hB, P + NG * HD);
  // layer 3: hB -> (pool only)
  gemm_scale_k<HD><<<(NN + 63) / 64, 256, 0, stream>>>(hB, W2, dinv, g);
  gather_k<false><<<(NN + 3) / 4, 256, 0, stream>>>(g, rowp, colb, dinv, b2, batch, hA, P + 2 * NG * HD);

  // JK cat + lin on pooled sums (linearity of pooling), then MLP head
  emb_k<<<(NG * HD + 255) / 256, 256, 0, stream>>>(P, gcnt, Wjk, bjk, emb);
  mlp1_k<<<(NG * HD + 255) / 256, 256, 0, stream>>>(emb, Wm1, bm1, hid);
  mlp2_k<<<(NG * OD + 255) / 256, 256, 0, stream>>>(hid, Wm2, bm2, (float*)d_out);
}

// Round 3
// 437.969 us; speedup vs baseline: 1.4121x; 1.1968x over previous
//
#include <hip/hip_runtime.h>

#define NN 50000
#define NE 800000
#define NG 500
#define IND 128
#define HD 96
#define OD 64

#define SCAN_CHUNK 2048
#define SCAN_BLOCKS ((NN + SCAN_CHUNK - 1) / SCAN_CHUNK)  // 25

// ---------------- CSR build ----------------

__global__ void zero_k(int* __restrict__ cnt, int* __restrict__ fill,
                       int* __restrict__ gcnt, float* __restrict__ P) {
  int i = blockIdx.x * 256 + threadIdx.x;
  if (i < NN) { cnt[i] = 0; fill[i] = 0; }
  if (i < NG) gcnt[i] = 0;
  if (i < 3 * NG * HD) P[i] = 0.f;
}

__global__ void hist_k(const int* __restrict__ dst, int* __restrict__ cnt) {
  int i = blockIdx.x * 256 + threadIdx.x;
  if (i < NE) atomicAdd(&cnt[dst[i]], 1);
}

__global__ void gcnt_k(const int* __restrict__ batch, int* __restrict__ gcnt) {
  int i = blockIdx.x * 256 + threadIdx.x;
  if (i < NN) atomicAdd(&gcnt[batch[i]], 1);
}

// phase 1: per-block partial sums over 2048-elem chunks; also dinv = rsqrt(deg+1)
__global__ __launch_bounds__(256) void scan_part_k(const int* __restrict__ cnt,
                                                   int* __restrict__ bsum,
                                                   float* __restrict__ dinv) {
  __shared__ int ts[256];
  const int tid = threadIdx.x;
  const int base = blockIdx.x * SCAN_CHUNK + tid * 8;
  int s = 0;
#pragma unroll
  for (int j = 0; j < 8; j++) {
    int idx = base + j;
    if (idx < NN) {
      int c = cnt[idx];
      s += c;
      dinv[idx] = rsqrtf((float)(c + 1));
    }
  }
  ts[tid] = s;
  __syncthreads();
  for (int off = 128; off > 0; off >>= 1) {
    if (tid < off) ts[tid] += ts[tid + off];
    __syncthreads();
  }
  if (tid == 0) bsum[blockIdx.x] = ts[0];
}

// phase 2: one wave scans the 25 block sums -> exclusive boff; row_ptr[NN]=NE
__global__ __launch_bounds__(64) void scan_top_k(const int* __restrict__ bsum,
                                                 int* __restrict__ boff,
                                                 int* __restrict__ row_ptr) {
  int tid = threadIdx.x;
  int v = (tid < SCAN_BLOCKS) ? bsum[tid] : 0;
  for (int off = 1; off < 64; off <<= 1) {
    int u = __shfl_up(v, off);
    if (tid >= off) v += u;
  }
  if (tid < SCAN_BLOCKS) boff[tid] = v - bsum[tid];  // exclusive
  if (tid == 0) row_ptr[NN] = NE;
}

// phase 3: per-block local exclusive scan + block offset -> row_ptr
__global__ __launch_bounds__(256) void scan_fin_k(const int* __restrict__ cnt,
                                                  const int* __restrict__ boff,
                                                  int* __restrict__ row_ptr) {
  __shared__ int ts[256];
  const int tid = threadIdx.x;
  const int base = blockIdx.x * SCAN_CHUNK + tid * 8;
  int v[8];
  int s = 0;
#pragma unroll
  for (int j = 0; j < 8; j++) {
    int idx = base + j;
    v[j] = (idx < NN) ? cnt[idx] : 0;
    s += v[j];
  }
  ts[tid] = s;
  __syncthreads();
  for (int off = 1; off < 256; off <<= 1) {
    int t = (tid >= off) ? ts[tid - off] : 0;
    __syncthreads();
    ts[tid] += t;
    __syncthreads();
  }
  int run = ((tid == 0) ? 0 : ts[tid - 1]) + boff[blockIdx.x];
#pragma unroll
  for (int j = 0; j < 8; j++) {
    int idx = base + j;
    if (idx < NN) row_ptr[idx] = run;
    run += v[j];
  }
}

__global__ void fill_k(const int* __restrict__ src, const int* __restrict__ dst,
                       const int* __restrict__ row_ptr, int* __restrict__ fill,
                       int* __restrict__ col) {
  int i = blockIdx.x * 256 + threadIdx.x;
  if (i < NE) {
    int d = dst[i];
    int slot = row_ptr[d] + atomicAdd(&fill[d], 1);
    col[slot] = src[i];
  }
}

// ---------------- g = (h @ W) * dinv[:,None]  (fp32, 8x8 register-tiled) ----------------
// BM=128 rows, BN=96 (all cols), BK=32. 192 threads = 16 rowg x 12 colg.
// A staged TRANSPOSED: hsT[k][row] so A-read is ds_read_b128; 1 LDS byte / FMA.
template <int K>
__global__ __launch_bounds__(192) void gemm_scale_k(const float* __restrict__ h,
                                                    const float* __restrict__ W,
                                                    const float* __restrict__ dinv,
                                                    float* __restrict__ g) {
  __shared__ __attribute__((aligned(16))) float hsT[32][132];  // stride 528B (16B-aligned)
  __shared__ __attribute__((aligned(16))) float ws[32][100];   // stride 400B (16B-aligned)
  const int tid = threadIdx.x;
  const int colg = tid % 12;
  const int rowg = tid / 12;
  const int row0 = blockIdx.x * 128;

  float acc[8][8];
#pragma unroll
  for (int i = 0; i < 8; i++)
#pragma unroll
    for (int j = 0; j < 8; j++) acc[i][j] = 0.f;

  for (int k0 = 0; k0 < K; k0 += 32) {
    // stage A transposed: 128 rows x 32 k = 1024 float4 loads
    for (int lin = tid; lin < 1024; lin += 192) {
      int r = lin >> 3, q = lin & 7;
      int grow = row0 + r;
      float4 v = make_float4(0.f, 0.f, 0.f, 0.f);
      if (grow < NN) v = *reinterpret_cast<const float4*>(&h[(long)grow * K + k0 + 4 * q]);
      hsT[4 * q + 0][r] = v.x;
      hsT[4 * q + 1][r] = v.y;
      hsT[4 * q + 2][r] = v.z;
      hsT[4 * q + 3][r] = v.w;
    }
    // stage W: 32 k x 24 float4 = 768
    for (int lin = tid; lin < 768; lin += 192) {
      int kk = lin / 24, c4 = lin - kk * 24;
      *reinterpret_cast<float4*>(&ws[kk][4 * c4]) =
          *reinterpret_cast<const float4*>(&W[(long)(k0 + kk) * HD + 4 * c4]);
    }
    __syncthreads();
#pragma unroll 8
    for (int k = 0; k < 32; k++) {
      float4 a0 = *reinterpret_cast<const float4*>(&hsT[k][8 * rowg]);
      float4 a1 = *reinterpret_cast<const float4*>(&hsT[k][8 * rowg + 4]);
      float4 w0 = *reinterpret_cast<const float4*>(&ws[k][8 * colg]);
      float4 w1 = *reinterpret_cast<const float4*>(&ws[k][8 * colg + 4]);
      float a[8] = {a0.x, a0.y, a0.z, a0.w, a1.x, a1.y, a1.z, a1.w};
      float w[8] = {w0.x, w0.y, w0.z, w0.w, w1.x, w1.y, w1.z, w1.w};
#pragma unroll
      for (int i = 0; i < 8; i++)
#pragma unroll
        for (int j = 0; j < 8; j++) acc[i][j] = fmaf(a[i], w[j], acc[i][j]);
    }
    __syncthreads();
  }
  // epilogue: scale by dinv[row], store 2 float4 per row
#pragma unroll
  for (int i = 0; i < 8; i++) {
    int row = row0 + 8 * rowg + i;
    if (row < NN) {
      float dv = dinv[row];
      float* go = g + (long)row * HD + 8 * colg;
      float4 o0, o1;
      o0.x = acc[i][0] * dv; o0.y = acc[i][1] * dv;
      o0.z = acc[i][2] * dv; o0.w = acc[i][3] * dv;
      o1.x = acc[i][4] * dv; o1.y = acc[i][5] * dv;
      o1.z = acc[i][6] * dv; o1.w = acc[i][7] * dv;
      *reinterpret_cast<float4*>(go) = o0;
      *reinterpret_cast<float4*>(go + 4) = o1;
    }
  }
}

// ---------------- CSR gather + relu + fused graph pooling ----------------
// one wave per node; lane l owns col l (and col 64+l for l<32)
template <bool WRITE_H>
__global__ __launch_bounds__(256) void gather_k(const float* __restrict__ g,
                                                const int* __restrict__ row_ptr,
                                                const int* __restrict__ col,
                                                const float* __restrict__ dinv,
                                                const float* __restrict__ bias,
                                                const int* __restrict__ batch,
                                                float* __restrict__ hout,
                                                float* __restrict__ P) {
  int d = blockIdx.x * 4 + (threadIdx.x >> 6);
  int lane = threadIdx.x & 63;
  if (d >= NN) return;
  const float* gd = g + (long)d * HD;
  float acc0 = gd[lane];                 // self-loop contribution
  float acc1 = gd[64 + (lane & 31)];     // lanes>=32 duplicate (broadcast)
  int e = row_ptr[d];
  const int end = row_ptr[d + 1];
  while (e < end) {
    int cnt = end - e; if (cnt > 64) cnt = 64;
    int cid = (lane < cnt) ? col[e + lane] : 0;
    for (int j = 0; j < cnt; j++) {
      int srow = __shfl(cid, j);
      const float* gs = g + (long)srow * HD;
      acc0 += gs[lane];
      acc1 += gs[64 + (lane & 31)];
    }
    e += 64;
  }
  float dv = dinv[d];
  int gr = batch[d];
  float v0 = fmaxf(fmaf(acc0, dv, bias[lane]), 0.f);
  if (WRITE_H) hout[(long)d * HD + lane] = v0;
  atomicAdd(&P[gr * HD + lane], v0);
  if (lane < 32) {
    float v1 = fmaxf(fmaf(acc1, dv, bias[64 + lane]), 0.f);
    if (WRITE_H) hout[(long)d * HD + 64 + lane] = v1;
    atomicAdd(&P[gr * HD + 64 + lane], v1);
  }
}

// ---------------- tiny dense tail: JK-proj on pooled sums + MLP ----------------

__global__ void emb_k(const float* __restrict__ P, const int* __restrict__ gcnt,
                      const float* __restrict__ Wjk, const float* __restrict__ bjk,
                      float* __restrict__ emb) {
  int idx = blockIdx.x * 256 + threadIdx.x;
  if (idx >= NG * HD) return;
  int gr = idx / HD, c = idx - gr * HD;
  const float* p1 = P + (long)gr * HD;
  const float* p2 = p1 + (long)NG * HD;
  const float* p3 = p2 + (long)NG * HD;
  float acc = (float)gcnt[gr] * bjk[c];
  for (int k = 0; k < HD; k++) {
    acc = fmaf(p1[k], Wjk[k * HD + c], acc);
    acc = fmaf(p2[k], Wjk[(HD + k) * HD + c], acc);
    acc = fmaf(p3[k], Wjk[(2 * HD + k) * HD + c], acc);
  }
  emb[idx] = acc;
}

__global__ void mlp1_k(const float* __restrict__ emb, const float* __restrict__ W,
                       const float* __restrict__ b, float* __restrict__ hid) {
  int idx = blockIdx.x * 256 + threadIdx.x;
  if (idx >= NG * HD) return;
  int gr = idx / HD, c = idx - gr * HD;
  const float* e = emb + (long)gr * HD;
  float acc = b[c];
  for (int k = 0; k < HD; k++) acc = fmaf(e[k], W[k * HD + c], acc);
  hid[idx] = fmaxf(acc, 0.f);
}

__global__ void mlp2_k(const float* __restrict__ hid, const float* __restrict__ W,
                       const float* __restrict__ b, float* __restrict__ out) {
  int idx = blockIdx.x * 256 + threadIdx.x;
  if (idx >= NG * OD) return;
  int gr = idx / OD, c = idx - gr * OD;
  const float* h = hid + (long)gr * HD;
  float acc = b[c];
  for (int k = 0; k < HD; k++) acc = fmaf(h[k], W[k * OD + c], acc);
  out[idx] = acc;
}

// ---------------- launch ----------------

extern "C" void kernel_launch(void* const* d_in, const int* in_sizes, int n_in,
                              void* d_out, int out_size, void* d_ws, size_t ws_size,
                              hipStream_t stream) {
  const float* x = (const float*)d_in[0];
  const int* ei = (const int*)d_in[1];
  const int* batch = (const int*)d_in[2];
  const float* W0 = (const float*)d_in[3];  const float* b0 = (const float*)d_in[4];
  const float* W1 = (const float*)d_in[5];  const float* b1 = (const float*)d_in[6];
  const float* W2 = (const float*)d_in[7];  const float* b2 = (const float*)d_in[8];
  const float* Wjk = (const float*)d_in[9]; const float* bjk = (const float*)d_in[10];
  const float* Wm1 = (const float*)d_in[11]; const float* bm1 = (const float*)d_in[12];
  const float* Wm2 = (const float*)d_in[13]; const float* bm2 = (const float*)d_in[14];
  const int* srcp = ei;
  const int* dstp = ei + NE;

  char* wp = (char*)d_ws;
  size_t off = 0;
  auto alloc = [&](size_t bytes) -> void* {
    void* p = wp + off;
    off += bytes;
    off = (off + 255) & ~(size_t)255;
    return p;
  };
  int* cnt   = (int*)alloc((size_t)NN * 4);
  int* rowp  = (int*)alloc((size_t)(NN + 1) * 4);
  int* fill  = (int*)alloc((size_t)NN * 4);
  int* colb  = (int*)alloc((size_t)NE * 4);
  float* dinv = (float*)alloc((size_t)NN * 4);
  int* gcnt  = (int*)alloc((size_t)NG * 4);
  int* bsum  = (int*)alloc((size_t)SCAN_BLOCKS * 4);
  int* boff  = (int*)alloc((size_t)SCAN_BLOCKS * 4);
  float* g   = (float*)alloc((size_t)NN * HD * 4);
  float* hA  = (float*)alloc((size_t)NN * HD * 4);
  float* hB  = (float*)alloc((size_t)NN * HD * 4);
  float* P   = (float*)alloc((size_t)3 * NG * HD * 4);
  float* emb = (float*)alloc((size_t)NG * HD * 4);
  float* hid = (float*)alloc((size_t)NG * HD * 4);

  // zero accumulators (must happen every call — harness does not re-poison)
  zero_k<<<(3 * NG * HD + 255) / 256, 256, 0, stream>>>(cnt, fill, gcnt, P);

  // CSR build + degrees (multi-block scan)
  hist_k<<<(NE + 255) / 256, 256, 0, stream>>>(dstp, cnt);
  gcnt_k<<<(NN + 255) / 256, 256, 0, stream>>>(batch, gcnt);
  scan_part_k<<<SCAN_BLOCKS, 256, 0, stream>>>(cnt, bsum, dinv);
  scan_top_k<<<1, 64, 0, stream>>>(bsum, boff, rowp);
  scan_fin_k<<<SCAN_BLOCKS, 256, 0, stream>>>(cnt, boff, rowp);
  fill_k<<<(NE + 255) / 256, 256, 0, stream>>>(srcp, dstp, rowp, fill, colb);

  const int gemm_grid = (NN + 127) / 128;
  // layer 1: x[50000,128] -> hA
  gemm_scale_k<IND><<<gemm_grid, 192, 0, stream>>>(x, W0, dinv, g);
  gather_k<true><<<(NN + 3) / 4, 256, 0, stream>>>(g, rowp, colb, dinv, b0, batch, hA, P);
  // layer 2: hA -> hB
  gemm_scale_k<HD><<<gemm_grid, 192, 0, stream>>>(hA, W1, dinv, g);
  gather_k<true><<<(NN + 3) / 4, 256, 0, stream>>>(g, rowp, colb, dinv, b1, batch, hB, P + NG * HD);
  // layer 3: hB -> (pool only)
  gemm_scale_k<HD><<<gemm_grid, 192, 0, stream>>>(hB, W2, dinv, g);
  gather_k<false><<<(NN + 3) / 4, 256, 0, stream>>>(g, rowp, colb, dinv, b2, batch, hA, P + 2 * NG * HD);

  // JK cat + lin on pooled sums (linearity of pooling), then MLP head
  emb_k<<<(NG * HD + 255) / 256, 256, 0, stream>>>(P, gcnt, Wjk, bjk, emb);
  mlp1_k<<<(NG * HD + 255) / 256, 256, 0, stream>>>(emb, Wm1, bm1, hid);
  mlp2_k<<<(NG * OD + 255) / 256, 256, 0, stream>>>(hid, Wm2, bm2, (float*)d_out);
}

// Round 4
// 391.515 us; speedup vs baseline: 1.5797x; 1.1187x over previous
//
#include <hip/hip_runtime.h>

#define NN 50000
#define NE 800000
#define NG 500
#define IND 128
#define HD 96
#define OD 64

#define SCAN_CHUNK 2048
#define SCAN_BLOCKS ((NN + SCAN_CHUNK - 1) / SCAN_CHUNK)  // 25

// ---------------- CSR build ----------------

__global__ void zero_k(int* __restrict__ cnt, int* __restrict__ fill,
                       int* __restrict__ gcnt, float* __restrict__ P) {
  int i = blockIdx.x * 256 + threadIdx.x;
  if (i < NN) { cnt[i] = 0; fill[i] = 0; }
  if (i < NG) gcnt[i] = 0;
  if (i < 3 * NG * HD) P[i] = 0.f;
}

__global__ void hist_k(const int* __restrict__ dst, int* __restrict__ cnt) {
  int i = blockIdx.x * 256 + threadIdx.x;
  if (i < NE) atomicAdd(&cnt[dst[i]], 1);
}

__global__ void gcnt_k(const int* __restrict__ batch, int* __restrict__ gcnt) {
  int i = blockIdx.x * 256 + threadIdx.x;
  if (i < NN) atomicAdd(&gcnt[batch[i]], 1);
}

// phase 1: per-block partial sums over 2048-elem chunks; also dinv = rsqrt(deg+1)
__global__ __launch_bounds__(256) void scan_part_k(const int* __restrict__ cnt,
                                                   int* __restrict__ bsum,
                                                   float* __restrict__ dinv) {
  __shared__ int ts[256];
  const int tid = threadIdx.x;
  const int base = blockIdx.x * SCAN_CHUNK + tid * 8;
  int s = 0;
#pragma unroll
  for (int j = 0; j < 8; j++) {
    int idx = base + j;
    if (idx < NN) {
      int c = cnt[idx];
      s += c;
      dinv[idx] = rsqrtf((float)(c + 1));
    }
  }
  ts[tid] = s;
  __syncthreads();
  for (int off = 128; off > 0; off >>= 1) {
    if (tid < off) ts[tid] += ts[tid + off];
    __syncthreads();
  }
  if (tid == 0) bsum[blockIdx.x] = ts[0];
}

// phase 2: one wave scans the 25 block sums -> exclusive boff; row_ptr[NN]=NE
__global__ __launch_bounds__(64) void scan_top_k(const int* __restrict__ bsum,
                                                 int* __restrict__ boff,
                                                 int* __restrict__ row_ptr) {
  int tid = threadIdx.x;
  int v = (tid < SCAN_BLOCKS) ? bsum[tid] : 0;
  for (int off = 1; off < 64; off <<= 1) {
    int u = __shfl_up(v, off);
    if (tid >= off) v += u;
  }
  if (tid < SCAN_BLOCKS) boff[tid] = v - bsum[tid];  // exclusive
  if (tid == 0) row_ptr[NN] = NE;
}

// phase 3: per-block local exclusive scan + block offset -> row_ptr
__global__ __launch_bounds__(256) void scan_fin_k(const int* __restrict__ cnt,
                                                  const int* __restrict__ boff,
                                                  int* __restrict__ row_ptr) {
  __shared__ int ts[256];
  const int tid = threadIdx.x;
  const int base = blockIdx.x * SCAN_CHUNK + tid * 8;
  int v[8];
  int s = 0;
#pragma unroll
  for (int j = 0; j < 8; j++) {
    int idx = base + j;
    v[j] = (idx < NN) ? cnt[idx] : 0;
    s += v[j];
  }
  ts[tid] = s;
  __syncthreads();
  for (int off = 1; off < 256; off <<= 1) {
    int t = (tid >= off) ? ts[tid - off] : 0;
    __syncthreads();
    ts[tid] += t;
    __syncthreads();
  }
  int run = ((tid == 0) ? 0 : ts[tid - 1]) + boff[blockIdx.x];
#pragma unroll
  for (int j = 0; j < 8; j++) {
    int idx = base + j;
    if (idx < NN) row_ptr[idx] = run;
    run += v[j];
  }
}

__global__ void fill_k(const int* __restrict__ src, const int* __restrict__ dst,
                       const int* __restrict__ row_ptr, int* __restrict__ fill,
                       int* __restrict__ col) {
  int i = blockIdx.x * 256 + threadIdx.x;
  if (i < NE) {
    int d = dst[i];
    int slot = row_ptr[d] + atomicAdd(&fill[d], 1);
    col[slot] = src[i];
  }
}

// ---------------- g = (h @ W) * dinv[:,None]  (fp32, 8x8 register-tiled) ----------------
// BM=128 rows, BN=96 (all cols), BK=32. 192 threads = 16 rowg x 12 colg.
// A staged TRANSPOSED: hsT[k][row] so A-read is ds_read_b128; 1 LDS byte / FMA.
template <int K>
__global__ __launch_bounds__(192) void gemm_scale_k(const float* __restrict__ h,
                                                    const float* __restrict__ W,
                                                    const float* __restrict__ dinv,
                                                    float* __restrict__ g) {
  __shared__ __attribute__((aligned(16))) float hsT[32][132];  // stride 528B (16B-aligned)
  __shared__ __attribute__((aligned(16))) float ws[32][100];   // stride 400B (16B-aligned)
  const int tid = threadIdx.x;
  const int colg = tid % 12;
  const int rowg = tid / 12;
  const int row0 = blockIdx.x * 128;

  float acc[8][8];
#pragma unroll
  for (int i = 0; i < 8; i++)
#pragma unroll
    for (int j = 0; j < 8; j++) acc[i][j] = 0.f;

  for (int k0 = 0; k0 < K; k0 += 32) {
    // stage A transposed: 128 rows x 32 k = 1024 float4 loads
    for (int lin = tid; lin < 1024; lin += 192) {
      int r = lin >> 3, q = lin & 7;
      int grow = row0 + r;
      float4 v = make_float4(0.f, 0.f, 0.f, 0.f);
      if (grow < NN) v = *reinterpret_cast<const float4*>(&h[(long)grow * K + k0 + 4 * q]);
      hsT[4 * q + 0][r] = v.x;
      hsT[4 * q + 1][r] = v.y;
      hsT[4 * q + 2][r] = v.z;
      hsT[4 * q + 3][r] = v.w;
    }
    // stage W: 32 k x 24 float4 = 768
    for (int lin = tid; lin < 768; lin += 192) {
      int kk = lin / 24, c4 = lin - kk * 24;
      *reinterpret_cast<float4*>(&ws[kk][4 * c4]) =
          *reinterpret_cast<const float4*>(&W[(long)(k0 + kk) * HD + 4 * c4]);
    }
    __syncthreads();
#pragma unroll 8
    for (int k = 0; k < 32; k++) {
      float4 a0 = *reinterpret_cast<const float4*>(&hsT[k][8 * rowg]);
      float4 a1 = *reinterpret_cast<const float4*>(&hsT[k][8 * rowg + 4]);
      float4 w0 = *reinterpret_cast<const float4*>(&ws[k][8 * colg]);
      float4 w1 = *reinterpret_cast<const float4*>(&ws[k][8 * colg + 4]);
      float a[8] = {a0.x, a0.y, a0.z, a0.w, a1.x, a1.y, a1.z, a1.w};
      float w[8] = {w0.x, w0.y, w0.z, w0.w, w1.x, w1.y, w1.z, w1.w};
#pragma unroll
      for (int i = 0; i < 8; i++)
#pragma unroll
        for (int j = 0; j < 8; j++) acc[i][j] = fmaf(a[i], w[j], acc[i][j]);
    }
    __syncthreads();
  }
  // epilogue: scale by dinv[row], store 2 float4 per row
#pragma unroll
  for (int i = 0; i < 8; i++) {
    int row = row0 + 8 * rowg + i;
    if (row < NN) {
      float dv = dinv[row];
      float* go = g + (long)row * HD + 8 * colg;
      float4 o0, o1;
      o0.x = acc[i][0] * dv; o0.y = acc[i][1] * dv;
      o0.z = acc[i][2] * dv; o0.w = acc[i][3] * dv;
      o1.x = acc[i][4] * dv; o1.y = acc[i][5] * dv;
      o1.z = acc[i][6] * dv; o1.w = acc[i][7] * dv;
      *reinterpret_cast<float4*>(go) = o0;
      *reinterpret_cast<float4*>(go + 4) = o1;
    }
  }
}

// ---------------- CSR gather + relu + fused graph pooling ----------------
// one wave per node; lane l owns col l (and col 64+l for l<32).
// Inner loop unrolled x8: 16 independent loads in flight per batch (MLP).
template <bool WRITE_H>
__global__ __launch_bounds__(256) void gather_k(const float* __restrict__ g,
                                                const int* __restrict__ row_ptr,
                                                const int* __restrict__ col,
                                                const float* __restrict__ dinv,
                                                const float* __restrict__ bias,
                                                const int* __restrict__ batch,
                                                float* __restrict__ hout,
                                                float* __restrict__ P) {
  int d = blockIdx.x * 4 + (threadIdx.x >> 6);
  int lane = threadIdx.x & 63;
  if (d >= NN) return;
  const float* gd = g + (long)d * HD;
  float acc0 = gd[lane];                 // self-loop contribution
  float acc1 = gd[64 + (lane & 31)];     // lanes>=32 duplicate (broadcast)
  int e = row_ptr[d];
  const int end = row_ptr[d + 1];
  const int lane2 = 64 + (lane & 31);
  while (e < end) {
    int cnt = end - e; if (cnt > 64) cnt = 64;
    int cid = (lane < cnt) ? col[e + lane] : 0;
    int j = 0;
    for (; j + 8 <= cnt; j += 8) {
      const float* gp0 = g + (long)__shfl(cid, j + 0) * HD;
      const float* gp1 = g + (long)__shfl(cid, j + 1) * HD;
      const float* gp2 = g + (long)__shfl(cid, j + 2) * HD;
      const float* gp3 = g + (long)__shfl(cid, j + 3) * HD;
      const float* gp4 = g + (long)__shfl(cid, j + 4) * HD;
      const float* gp5 = g + (long)__shfl(cid, j + 5) * HD;
      const float* gp6 = g + (long)__shfl(cid, j + 6) * HD;
      const float* gp7 = g + (long)__shfl(cid, j + 7) * HD;
      float a0 = gp0[lane], a1 = gp1[lane], a2 = gp2[lane], a3 = gp3[lane];
      float a4 = gp4[lane], a5 = gp5[lane], a6 = gp6[lane], a7 = gp7[lane];
      float b0 = gp0[lane2], b1 = gp1[lane2], b2 = gp2[lane2], b3 = gp3[lane2];
      float b4 = gp4[lane2], b5 = gp5[lane2], b6 = gp6[lane2], b7 = gp7[lane2];
      acc0 += ((a0 + a1) + (a2 + a3)) + ((a4 + a5) + (a6 + a7));
      acc1 += ((b0 + b1) + (b2 + b3)) + ((b4 + b5) + (b6 + b7));
    }
    for (; j < cnt; j++) {
      int srow = __shfl(cid, j);
      const float* gs = g + (long)srow * HD;
      acc0 += gs[lane];
      acc1 += gs[lane2];
    }
    e += 64;
  }
  float dv = dinv[d];
  int gr = batch[d];
  float v0 = fmaxf(fmaf(acc0, dv, bias[lane]), 0.f);
  if (WRITE_H) hout[(long)d * HD + lane] = v0;
  atomicAdd(&P[gr * HD + lane], v0);
  if (lane < 32) {
    float v1 = fmaxf(fmaf(acc1, dv, bias[64 + lane]), 0.f);
    if (WRITE_H) hout[(long)d * HD + 64 + lane] = v1;
    atomicAdd(&P[gr * HD + 64 + lane], v1);
  }
}

// ---------------- tiny dense tail: JK-proj on pooled sums + MLP ----------------

__global__ void emb_k(const float* __restrict__ P, const int* __restrict__ gcnt,
                      const float* __restrict__ Wjk, const float* __restrict__ bjk,
                      float* __restrict__ emb) {
  int idx = blockIdx.x * 256 + threadIdx.x;
  if (idx >= NG * HD) return;
  int gr = idx / HD, c = idx - gr * HD;
  const float* p1 = P + (long)gr * HD;
  const float* p2 = p1 + (long)NG * HD;
  const float* p3 = p2 + (long)NG * HD;
  float acc = (float)gcnt[gr] * bjk[c];
  for (int k = 0; k < HD; k++) {
    acc = fmaf(p1[k], Wjk[k * HD + c], acc);
    acc = fmaf(p2[k], Wjk[(HD + k) * HD + c], acc);
    acc = fmaf(p3[k], Wjk[(2 * HD + k) * HD + c], acc);
  }
  emb[idx] = acc;
}

__global__ void mlp1_k(const float* __restrict__ emb, const float* __restrict__ W,
                       const float* __restrict__ b, float* __restrict__ hid) {
  int idx = blockIdx.x * 256 + threadIdx.x;
  if (idx >= NG * HD) return;
  int gr = idx / HD, c = idx - gr * HD;
  const float* e = emb + (long)gr * HD;
  float acc = b[c];
  for (int k = 0; k < HD; k++) acc = fmaf(e[k], W[k * HD + c], acc);
  hid[idx] = fmaxf(acc, 0.f);
}

__global__ void mlp2_k(const float* __restrict__ hid, const float* __restrict__ W,
                       const float* __restrict__ b, float* __restrict__ out) {
  int idx = blockIdx.x * 256 + threadIdx.x;
  if (idx >= NG * OD) return;
  int gr = idx / OD, c = idx - gr * OD;
  const float* h = hid + (long)gr * HD;
  float acc = b[c];
  for (int k = 0; k < HD; k++) acc = fmaf(h[k], W[k * OD + c], acc);
  out[idx] = acc;
}

// ---------------- launch ----------------

extern "C" void kernel_launch(void* const* d_in, const int* in_sizes, int n_in,
                              void* d_out, int out_size, void* d_ws, size_t ws_size,
                              hipStream_t stream) {
  const float* x = (const float*)d_in[0];
  const int* ei = (const int*)d_in[1];
  const int* batch = (const int*)d_in[2];
  const float* W0 = (const float*)d_in[3];  const float* b0 = (const float*)d_in[4];
  const float* W1 = (const float*)d_in[5];  const float* b1 = (const float*)d_in[6];
  const float* W2 = (const float*)d_in[7];  const float* b2 = (const float*)d_in[8];
  const float* Wjk = (const float*)d_in[9]; const float* bjk = (const float*)d_in[10];
  const float* Wm1 = (const float*)d_in[11]; const float* bm1 = (const float*)d_in[12];
  const float* Wm2 = (const float*)d_in[13]; const float* bm2 = (const float*)d_in[14];
  const int* srcp = ei;
  const int* dstp = ei + NE;

  char* wp = (char*)d_ws;
  size_t off = 0;
  auto alloc = [&](size_t bytes) -> void* {
    void* p = wp + off;
    off += bytes;
    off = (off + 255) & ~(size_t)255;
    return p;
  };
  int* cnt   = (int*)alloc((size_t)NN * 4);
  int* rowp  = (int*)alloc((size_t)(NN + 1) * 4);
  int* fill  = (int*)alloc((size_t)NN * 4);
  int* colb  = (int*)alloc((size_t)NE * 4);
  float* dinv = (float*)alloc((size_t)NN * 4);
  int* gcnt  = (int*)alloc((size_t)NG * 4);
  int* bsum  = (int*)alloc((size_t)SCAN_BLOCKS * 4);
  int* boff  = (int*)alloc((size_t)SCAN_BLOCKS * 4);
  float* g   = (float*)alloc((size_t)NN * HD * 4);
  float* hA  = (float*)alloc((size_t)NN * HD * 4);
  float* hB  = (float*)alloc((size_t)NN * HD * 4);
  float* P   = (float*)alloc((size_t)3 * NG * HD * 4);
  float* emb = (float*)alloc((size_t)NG * HD * 4);
  float* hid = (float*)alloc((size_t)NG * HD * 4);

  // zero accumulators (must happen every call — harness does not re-poison)
  zero_k<<<(3 * NG * HD + 255) / 256, 256, 0, stream>>>(cnt, fill, gcnt, P);

  // CSR build + degrees (multi-block scan)
  hist_k<<<(NE + 255) / 256, 256, 0, stream>>>(dstp, cnt);
  gcnt_k<<<(NN + 255) / 256, 256, 0, stream>>>(batch, gcnt);
  scan_part_k<<<SCAN_BLOCKS, 256, 0, stream>>>(cnt, bsum, dinv);
  scan_top_k<<<1, 64, 0, stream>>>(bsum, boff, rowp);
  scan_fin_k<<<SCAN_BLOCKS, 256, 0, stream>>>(cnt, boff, rowp);
  fill_k<<<(NE + 255) / 256, 256, 0, stream>>>(srcp, dstp, rowp, fill, colb);

  const int gemm_grid = (NN + 127) / 128;
  // layer 1: x[50000,128] -> hA
  gemm_scale_k<IND><<<gemm_grid, 192, 0, stream>>>(x, W0, dinv, g);
  gather_k<true><<<(NN + 3) / 4, 256, 0, stream>>>(g, rowp, colb, dinv, b0, batch, hA, P);
  // layer 2: hA -> hB
  gemm_scale_k<HD><<<gemm_grid, 192, 0, stream>>>(hA, W1, dinv, g);
  gather_k<true><<<(NN + 3) / 4, 256, 0, stream>>>(g, rowp, colb, dinv, b1, batch, hB, P + NG * HD);
  // layer 3: hB -> (pool only)
  gemm_scale_k<HD><<<gemm_grid, 192, 0, stream>>>(hB, W2, dinv, g);
  gather_k<false><<<(NN + 3) / 4, 256, 0, stream>>>(g, rowp, colb, dinv, b2, batch, hA, P + 2 * NG * HD);

  // JK cat + lin on pooled sums (linearity of pooling), then MLP head
  emb_k<<<(NG * HD + 255) / 256, 256, 0, stream>>>(P, gcnt, Wjk, bjk, emb);
  mlp1_k<<<(NG * HD + 255) / 256, 256, 0, stream>>>(emb, Wm1, bm1, hid);
  mlp2_k<<<(NG * OD + 255) / 256, 256, 0, stream>>>(hid, Wm2, bm2, (float*)d_out);
}